// Round 3
// baseline (927.817 us; speedup 1.0000x reference)
//
#include <hip/hip_runtime.h>

// ---- problem constants (fixed by reference setup_inputs) ----
constexpr int B_  = 32;
constexpr int Na  = 512;
constexpr int Nv  = 256;
constexpr int D   = 384;

constexpr int BK  = 32;        // k-chunk per iteration
constexpr int BN  = 128;       // audio rows per block (one n-chunk)
constexpr int NK  = D / BK;    // 12 k-iters
constexpr int NCH = Na / BN;   // 4 n-chunks -> grid = 32*32*4

typedef short  bf16x8  __attribute__((ext_vector_type(8)));
typedef float  floatx4 __attribute__((ext_vector_type(4)));
typedef unsigned short ushort8v __attribute__((ext_vector_type(8)));

// fp32 -> bf16 round-to-nearest-even
__device__ __forceinline__ unsigned short f2bf(float f) {
    unsigned int u = __float_as_uint(f);
    u += 0x7fffu + ((u >> 16) & 1u);
    return (unsigned short)(u >> 16);
}

// 16B-per-lane async global->LDS (lane i writes LDS slot base + i*16)
__device__ __forceinline__ void async_load16(const void* g, void* l) {
    __builtin_amdgcn_global_load_lds(
        (const __attribute__((address_space(1))) unsigned int*)g,
        (__attribute__((address_space(3))) unsigned int*)l,
        16, 0, 0);
}

// ---- K1: zero output + one-shot fp32 -> bf16 conversion into workspace ----
__global__ void convert_kernel(const float* __restrict__ a, const float* __restrict__ v,
                               unsigned short* __restrict__ abf, unsigned short* __restrict__ vbf,
                               float* __restrict__ out) {
    constexpr int NA8 = B_ * Na * D / 8;   // 786,432 float8 groups
    constexpr int NV8 = B_ * Nv * D / 8;   // 393,216
    int gid = blockIdx.x * blockDim.x + threadIdx.x;
    if (gid < B_ * B_) out[gid] = 0.0f;    // d_out is poisoned before every launch
    int stride = gridDim.x * blockDim.x;
    for (int i = gid; i < NA8 + NV8; i += stride) {
        const float4* src;
        unsigned short* dst;
        int j;
        if (i < NA8) { src = (const float4*)a; dst = abf; j = i; }
        else         { src = (const float4*)v; dst = vbf; j = i - NA8; }
        float4 f0 = src[2 * j];
        float4 f1 = src[2 * j + 1];
        ushort8v o = { f2bf(f0.x), f2bf(f0.y), f2bf(f0.z), f2bf(f0.w),
                       f2bf(f1.x), f2bf(f1.y), f2bf(f1.z), f2bf(f1.w) };
        *(ushort8v*)&dst[j * 8] = o;
    }
}

// ---- K2: fused bf16 GEMM + logsumexp-pool ----
// A fragments load straight from global into registers (prefetched 1 iter ahead).
// B is double-buffered in LDS via global_load_lds; ONE barrier per k-iter, placed
// so the vmcnt(0) drain only waits on loads issued a full compute-phase earlier.
// LDS layout (per 16-row group g): addr(row r, chunk c) = g*1024 + c*256 + r*16,
// matching global_load_lds lane order; ds_read_b128 hits only the free 2-way alias.
__global__ __launch_bounds__(256, 4) void gemm_lse_kernel(
        const unsigned short* __restrict__ abf,
        const unsigned short* __restrict__ vbf,
        float* __restrict__ out)
{
    __shared__ unsigned short blds[2][Nv * BK];   // 2 x 16 KB
    __shared__ float wsum[4];

    // XCD-swizzled block decode: xcd x owns bj in [4x, 4x+4); bi-major within xcd
    const int x   = blockIdx.x & 7;
    const int s   = blockIdx.x >> 3;
    const int bi  = s >> 4;
    const int bj  = x * 4 + ((s >> 2) & 3);
    const int nc  = s & 3;

    const int tid  = threadIdx.x;
    const int lane = tid & 63;
    const int wave = tid >> 6;
    const int fr   = lane & 15;    // free index within a 16-tile / staging row-in-group
    const int g    = lane >> 4;    // k-quarter / staging chunk index

    const unsigned short* Ab = abf + ((size_t)bi * Na + nc * BN) * D;
    const unsigned short* Bb = vbf + (size_t)bj * Nv * D;

    // B staging source pointers (global) + uniform LDS group bases
    const unsigned short* bg[4];
    #pragma unroll
    for (int q = 0; q < 4; ++q)
        bg[q] = Bb + (size_t)((wave * 4 + q) * 16 + fr) * D + g * 8;

    // A fragment global addresses (per-lane 16B, row-scattered but L2-resident)
    const unsigned short* aptr0 = Ab + (size_t)(wave * 32 +      fr) * D + g * 8;
    const unsigned short* aptr1 = Ab + (size_t)(wave * 32 + 16 + fr) * D + g * 8;

    // ---- prologue: issue B[0], load A[0] ----
    #pragma unroll
    for (int q = 0; q < 4; ++q)
        async_load16(bg[q], (void*)&blds[0][(wave * 4 + q) * 512]);
    bf16x8 a0 = *(const bf16x8*)aptr0;
    bf16x8 a1 = *(const bf16x8*)aptr1;

    floatx4 acc[2][16];
    #pragma unroll
    for (int a = 0; a < 2; ++a)
        #pragma unroll
        for (int mt = 0; mt < 16; ++mt)
            acc[a][mt] = (floatx4){0.f, 0.f, 0.f, 0.f};

    #pragma unroll
    for (int k = 0; k < NK; ++k) {
        // drains vmcnt(0): waits on B[k]/A[k-prefetches] issued one compute-phase ago
        __syncthreads();

        bf16x8 na0 = a0, na1 = a1;
        if (k + 1 < NK) {
            #pragma unroll
            for (int q = 0; q < 4; ++q)
                async_load16(bg[q] + (k + 1) * BK,
                             (void*)&blds[(k + 1) & 1][(wave * 4 + q) * 512]);
            na0 = *(const bf16x8*)(aptr0 + (k + 1) * BK);
            na1 = *(const bf16x8*)(aptr1 + (k + 1) * BK);
        }

        const unsigned short* buf = blds[k & 1];
        #pragma unroll
        for (int mt = 0; mt < 16; ++mt) {
            bf16x8 bfr = *(const bf16x8*)&buf[mt * 512 + g * 128 + fr * 8];
            acc[0][mt] = __builtin_amdgcn_mfma_f32_16x16x32_bf16(a0, bfr, acc[0][mt], 0, 0, 0);
            acc[1][mt] = __builtin_amdgcn_mfma_f32_16x16x32_bf16(a1, bfr, acc[1][mt], 0, 0, 0);
        }
        a0 = na0; a1 = na1;
    }

    // ---- epilogue: per-row logsumexp over all 256 cols ----
    // C/D layout: col = mt*16 + (lane&15), row = (lane>>4)*4 + reg
    constexpr float INV_TAU_LN2 = 0.7213475204444817f;  // 1/(tau*ln2), tau=2
    constexpr float TAU_LN2     = 1.3862943611198906f;  // tau*ln2

    float row_acc = 0.0f;
    #pragma unroll
    for (int a = 0; a < 2; ++a) {
        #pragma unroll
        for (int r = 0; r < 4; ++r) {
            float vmax = acc[a][0][r];
            #pragma unroll
            for (int mt = 1; mt < 16; ++mt) vmax = fmaxf(vmax, acc[a][mt][r]);
            #pragma unroll
            for (int m = 1; m < 16; m <<= 1)
                vmax = fmaxf(vmax, __shfl_xor(vmax, m, 64));
            float s2 = 0.f;
            #pragma unroll
            for (int mt = 0; mt < 16; ++mt)
                s2 += exp2f((acc[a][mt][r] - vmax) * INV_TAU_LN2);
            #pragma unroll
            for (int m = 1; m < 16; m <<= 1)
                s2 += __shfl_xor(s2, m, 64);
            row_acc += vmax + TAU_LN2 * log2f(s2);
        }
    }

    row_acc += __shfl_xor(row_acc, 16, 64);
    row_acc += __shfl_xor(row_acc, 32, 64);
    if (lane == 0) wsum[wave] = row_acc;
    __syncthreads();
    if (tid == 0)
        atomicAdd(&out[bi * 32 + bj],
                  (wsum[0] + wsum[1] + wsum[2] + wsum[3]) * (1.0f / Na));
}

extern "C" void kernel_launch(void* const* d_in, const int* in_sizes, int n_in,
                              void* d_out, int out_size, void* d_ws, size_t ws_size,
                              hipStream_t stream) {
    const float* audio  = (const float*)d_in[0];
    const float* visual = (const float*)d_in[1];
    float* out = (float*)d_out;

    unsigned short* abf = (unsigned short*)d_ws;                 // 12.58 MB
    unsigned short* vbf = abf + (size_t)B_ * Na * D;             // +6.29 MB

    convert_kernel<<<dim3(2048), dim3(256), 0, stream>>>(audio, visual, abf, vbf, out);
    gemm_lse_kernel<<<dim3(B_ * B_ * NCH), dim3(256), 0, stream>>>(abf, vbf, out);
}

// Round 4
// 320.232 us; speedup vs baseline: 2.8973x; 2.8973x over previous
//
#include <hip/hip_runtime.h>

// ---- problem constants (fixed by reference setup_inputs) ----
constexpr int B_  = 32;
constexpr int Na  = 512;
constexpr int Nv  = 256;
constexpr int D   = 384;

constexpr int BK  = 32;        // k-chunk per iteration
constexpr int BN  = 128;       // audio rows per block (one n-chunk)
constexpr int NK  = D / BK;    // 12 k-iters
constexpr int NCH = Na / BN;   // 4 n-chunks -> grid = 32*32*4

typedef short  bf16x8  __attribute__((ext_vector_type(8)));
typedef float  floatx4 __attribute__((ext_vector_type(4)));
typedef unsigned short ushort8v __attribute__((ext_vector_type(8)));

// fp32 -> bf16 round-to-nearest-even
__device__ __forceinline__ unsigned short f2bf(float f) {
    unsigned int u = __float_as_uint(f);
    u += 0x7fffu + ((u >> 16) & 1u);
    return (unsigned short)(u >> 16);
}

// 16B-per-lane async global->LDS (lane i writes LDS slot base + i*16)
__device__ __forceinline__ void async_load16(const void* g, void* l) {
    __builtin_amdgcn_global_load_lds(
        (const __attribute__((address_space(1))) unsigned int*)g,
        (__attribute__((address_space(3))) unsigned int*)l,
        16, 0, 0);
}

// ---- K1: zero output + one-shot fp32 -> bf16 conversion into workspace ----
__global__ void convert_kernel(const float* __restrict__ a, const float* __restrict__ v,
                               unsigned short* __restrict__ abf, unsigned short* __restrict__ vbf,
                               float* __restrict__ out) {
    constexpr int NA8 = B_ * Na * D / 8;   // 786,432 float8 groups
    constexpr int NV8 = B_ * Nv * D / 8;   // 393,216
    int gid = blockIdx.x * blockDim.x + threadIdx.x;
    if (gid < B_ * B_) out[gid] = 0.0f;    // d_out is poisoned before every launch
    int stride = gridDim.x * blockDim.x;
    for (int i = gid; i < NA8 + NV8; i += stride) {
        const float4* src;
        unsigned short* dst;
        int j;
        if (i < NA8) { src = (const float4*)a; dst = abf; j = i; }
        else         { src = (const float4*)v; dst = vbf; j = i - NA8; }
        float4 f0 = src[2 * j];
        float4 f1 = src[2 * j + 1];
        ushort8v o = { f2bf(f0.x), f2bf(f0.y), f2bf(f0.z), f2bf(f0.w),
                       f2bf(f1.x), f2bf(f1.y), f2bf(f1.z), f2bf(f1.w) };
        *(ushort8v*)&dst[j * 8] = o;
    }
}

// ---- K2: fused bf16 GEMM + logsumexp-pool ----
// A fragments load straight from global into registers (prefetched 1 iter ahead).
// B is double-buffered in LDS via global_load_lds; ONE barrier per k-iter, placed
// so the vmcnt(0) drain only waits on loads issued a full compute-phase earlier.
// __launch_bounds__(256,3): ~170 unified regs/wave — acc[2][16] (128 AGPRs) +
// addressing fits WITHOUT scratch spill. (256,4) = 128-reg cap -> acc spills to
// scratch -> 2.5 GB/dispatch writes, 4x regression (measured round 3).
__global__ __launch_bounds__(256, 3) void gemm_lse_kernel(
        const unsigned short* __restrict__ abf,
        const unsigned short* __restrict__ vbf,
        float* __restrict__ out)
{
    __shared__ unsigned short blds[2][Nv * BK];   // 2 x 16 KB
    __shared__ float wsum[4];

    // XCD-swizzled block decode: xcd x owns bj in [4x, 4x+4); bi-major within xcd
    const int x   = blockIdx.x & 7;
    const int s   = blockIdx.x >> 3;
    const int bi  = s >> 4;
    const int bj  = x * 4 + ((s >> 2) & 3);
    const int nc  = s & 3;

    const int tid  = threadIdx.x;
    const int lane = tid & 63;
    const int wave = tid >> 6;
    const int fr   = lane & 15;    // free index within a 16-tile / staging row-in-group
    const int g    = lane >> 4;    // k-quarter / staging chunk index

    const unsigned short* Ab = abf + ((size_t)bi * Na + nc * BN) * D;
    const unsigned short* Bb = vbf + (size_t)bj * Nv * D;

    // B staging source pointers (global) + uniform LDS group bases
    const unsigned short* bg[4];
    #pragma unroll
    for (int q = 0; q < 4; ++q)
        bg[q] = Bb + (size_t)((wave * 4 + q) * 16 + fr) * D + g * 8;

    // A fragment global addresses (per-lane 16B, row-scattered but L2-resident)
    const unsigned short* aptr0 = Ab + (size_t)(wave * 32 +      fr) * D + g * 8;
    const unsigned short* aptr1 = Ab + (size_t)(wave * 32 + 16 + fr) * D + g * 8;

    // ---- prologue: issue B[0], load A[0] ----
    #pragma unroll
    for (int q = 0; q < 4; ++q)
        async_load16(bg[q], (void*)&blds[0][(wave * 4 + q) * 512]);
    bf16x8 a0 = *(const bf16x8*)aptr0;
    bf16x8 a1 = *(const bf16x8*)aptr1;

    floatx4 acc[2][16];
    #pragma unroll
    for (int a = 0; a < 2; ++a)
        #pragma unroll
        for (int mt = 0; mt < 16; ++mt)
            acc[a][mt] = (floatx4){0.f, 0.f, 0.f, 0.f};

    #pragma unroll
    for (int k = 0; k < NK; ++k) {
        // drains vmcnt(0): waits on B[k]/A-prefetches issued one compute-phase ago
        __syncthreads();

        bf16x8 na0 = a0, na1 = a1;
        if (k + 1 < NK) {
            #pragma unroll
            for (int q = 0; q < 4; ++q)
                async_load16(bg[q] + (k + 1) * BK,
                             (void*)&blds[(k + 1) & 1][(wave * 4 + q) * 512]);
            na0 = *(const bf16x8*)(aptr0 + (k + 1) * BK);
            na1 = *(const bf16x8*)(aptr1 + (k + 1) * BK);
        }

        const unsigned short* buf = blds[k & 1];
        #pragma unroll
        for (int mt = 0; mt < 16; ++mt) {
            bf16x8 bfr = *(const bf16x8*)&buf[mt * 512 + g * 128 + fr * 8];
            acc[0][mt] = __builtin_amdgcn_mfma_f32_16x16x32_bf16(a0, bfr, acc[0][mt], 0, 0, 0);
            acc[1][mt] = __builtin_amdgcn_mfma_f32_16x16x32_bf16(a1, bfr, acc[1][mt], 0, 0, 0);
        }
        a0 = na0; a1 = na1;
    }

    // ---- epilogue: per-row logsumexp over all 256 cols ----
    // C/D layout: col = mt*16 + (lane&15), row = (lane>>4)*4 + reg
    constexpr float INV_TAU_LN2 = 0.7213475204444817f;  // 1/(tau*ln2), tau=2
    constexpr float TAU_LN2     = 1.3862943611198906f;  // tau*ln2

    float row_acc = 0.0f;
    #pragma unroll
    for (int a = 0; a < 2; ++a) {
        #pragma unroll
        for (int r = 0; r < 4; ++r) {
            float vmax = acc[a][0][r];
            #pragma unroll
            for (int mt = 1; mt < 16; ++mt) vmax = fmaxf(vmax, acc[a][mt][r]);
            #pragma unroll
            for (int m = 1; m < 16; m <<= 1)
                vmax = fmaxf(vmax, __shfl_xor(vmax, m, 64));
            float s2 = 0.f;
            #pragma unroll
            for (int mt = 0; mt < 16; ++mt)
                s2 += exp2f((acc[a][mt][r] - vmax) * INV_TAU_LN2);
            #pragma unroll
            for (int m = 1; m < 16; m <<= 1)
                s2 += __shfl_xor(s2, m, 64);
            row_acc += vmax + TAU_LN2 * log2f(s2);
        }
    }

    row_acc += __shfl_xor(row_acc, 16, 64);
    row_acc += __shfl_xor(row_acc, 32, 64);
    if (lane == 0) wsum[wave] = row_acc;
    __syncthreads();
    if (tid == 0)
        atomicAdd(&out[bi * 32 + bj],
                  (wsum[0] + wsum[1] + wsum[2] + wsum[3]) * (1.0f / Na));
}

extern "C" void kernel_launch(void* const* d_in, const int* in_sizes, int n_in,
                              void* d_out, int out_size, void* d_ws, size_t ws_size,
                              hipStream_t stream) {
    const float* audio  = (const float*)d_in[0];
    const float* visual = (const float*)d_in[1];
    float* out = (float*)d_out;

    unsigned short* abf = (unsigned short*)d_ws;                 // 12.58 MB
    unsigned short* vbf = abf + (size_t)B_ * Na * D;             // +6.29 MB

    convert_kernel<<<dim3(2048), dim3(256), 0, stream>>>(audio, visual, abf, vbf, out);
    gemm_lse_kernel<<<dim3(B_ * B_ * NCH), dim3(256), 0, stream>>>(abf, vbf, out);
}

// Round 5
// 268.755 us; speedup vs baseline: 3.4523x; 1.1915x over previous
//
#include <hip/hip_runtime.h>

// ---- problem constants (fixed by reference setup_inputs) ----
constexpr int B_  = 32;
constexpr int Na  = 512;
constexpr int Nv  = 256;
constexpr int D   = 384;

constexpr int BK  = 32;        // k-chunk per iteration
constexpr int BN  = 128;       // audio rows per block (one n-chunk)
constexpr int NK  = D / BK;    // 12 k-iters
constexpr int NCH = Na / BN;   // 4 n-chunks -> grid = 32*32*4

typedef short  bf16x8  __attribute__((ext_vector_type(8)));
typedef float  floatx4 __attribute__((ext_vector_type(4)));
typedef unsigned short ushort8v __attribute__((ext_vector_type(8)));

// fp32 -> bf16 round-to-nearest-even
__device__ __forceinline__ unsigned short f2bf(float f) {
    unsigned int u = __float_as_uint(f);
    u += 0x7fffu + ((u >> 16) & 1u);
    return (unsigned short)(u >> 16);
}

// 16B-per-lane async global->LDS (lane i writes LDS slot base + i*16)
__device__ __forceinline__ void async_load16(const void* g, void* l) {
    __builtin_amdgcn_global_load_lds(
        (const __attribute__((address_space(1))) unsigned int*)g,
        (__attribute__((address_space(3))) unsigned int*)l,
        16, 0, 0);
}

// ---- K1: zero output + one-shot fp32 -> bf16 conversion into workspace ----
__global__ void convert_kernel(const float* __restrict__ a, const float* __restrict__ v,
                               unsigned short* __restrict__ abf, unsigned short* __restrict__ vbf,
                               float* __restrict__ out) {
    constexpr int NA8 = B_ * Na * D / 8;   // 786,432 float8 groups
    constexpr int NV8 = B_ * Nv * D / 8;   // 393,216
    int gid = blockIdx.x * blockDim.x + threadIdx.x;
    if (gid < B_ * B_) out[gid] = 0.0f;    // d_out is poisoned before every launch
    int stride = gridDim.x * blockDim.x;
    for (int i = gid; i < NA8 + NV8; i += stride) {
        const float4* src;
        unsigned short* dst;
        int j;
        if (i < NA8) { src = (const float4*)a; dst = abf; j = i; }
        else         { src = (const float4*)v; dst = vbf; j = i - NA8; }
        float4 f0 = src[2 * j];
        float4 f1 = src[2 * j + 1];
        ushort8v o = { f2bf(f0.x), f2bf(f0.y), f2bf(f0.z), f2bf(f0.w),
                       f2bf(f1.x), f2bf(f1.y), f2bf(f1.z), f2bf(f1.w) };
        *(ushort8v*)&dst[j * 8] = o;
    }
}

// ---- K2: fused bf16 GEMM + logsumexp-pool ----
// A fragments load straight from global into registers (prefetched 1 iter ahead).
// B is double-buffered in LDS via global_load_lds; ONE barrier per k-iter, placed
// so the vmcnt(0) drain only waits on loads issued a full compute-phase earlier.
// REGISTER BUDGET (the round-3/4 lesson): acc[2][16] = 128 AGPRs + ~84 VGPRs =
// 212 regs/wave. gfx950 unified file = 512/SIMD:
//   bound 4 -> 128/wave cap -> catastrophic spill (2.5 GB scratch, round 3)
//   bound 3 -> 170/wave cap -> moderate spill  (375 MB scratch, round 4)
//   bound 2 -> 256/wave cap -> fits with slack (this round)
__global__ __launch_bounds__(256, 2) void gemm_lse_kernel(
        const unsigned short* __restrict__ abf,
        const unsigned short* __restrict__ vbf,
        float* __restrict__ out)
{
    __shared__ unsigned short blds[2][Nv * BK];   // 2 x 16 KB
    __shared__ float wsum[4];

    // XCD-swizzled block decode: xcd x owns bj in [4x, 4x+4); bi-major within xcd
    const int x   = blockIdx.x & 7;
    const int s   = blockIdx.x >> 3;
    const int bi  = s >> 4;
    const int bj  = x * 4 + ((s >> 2) & 3);
    const int nc  = s & 3;

    const int tid  = threadIdx.x;
    const int lane = tid & 63;
    const int wave = tid >> 6;
    const int fr   = lane & 15;    // free index within a 16-tile / staging row-in-group
    const int g    = lane >> 4;    // k-quarter / staging chunk index

    const unsigned short* Ab = abf + ((size_t)bi * Na + nc * BN) * D;
    const unsigned short* Bb = vbf + (size_t)bj * Nv * D;

    // B staging source pointers (global) + uniform LDS group bases
    const unsigned short* bg[4];
    #pragma unroll
    for (int q = 0; q < 4; ++q)
        bg[q] = Bb + (size_t)((wave * 4 + q) * 16 + fr) * D + g * 8;

    // A fragment global addresses (per-lane 16B, row-scattered but L2-resident)
    const unsigned short* aptr0 = Ab + (size_t)(wave * 32 +      fr) * D + g * 8;
    const unsigned short* aptr1 = Ab + (size_t)(wave * 32 + 16 + fr) * D + g * 8;

    // ---- prologue: issue B[0], load A[0] ----
    #pragma unroll
    for (int q = 0; q < 4; ++q)
        async_load16(bg[q], (void*)&blds[0][(wave * 4 + q) * 512]);
    bf16x8 a0 = *(const bf16x8*)aptr0;
    bf16x8 a1 = *(const bf16x8*)aptr1;

    floatx4 acc[2][16];
    #pragma unroll
    for (int a = 0; a < 2; ++a)
        #pragma unroll
        for (int mt = 0; mt < 16; ++mt)
            acc[a][mt] = (floatx4){0.f, 0.f, 0.f, 0.f};

    #pragma unroll
    for (int k = 0; k < NK; ++k) {
        // drains vmcnt(0): waits on B[k]/A-prefetches issued one compute-phase ago
        __syncthreads();

        bf16x8 na0 = a0, na1 = a1;
        if (k + 1 < NK) {
            #pragma unroll
            for (int q = 0; q < 4; ++q)
                async_load16(bg[q] + (k + 1) * BK,
                             (void*)&blds[(k + 1) & 1][(wave * 4 + q) * 512]);
            na0 = *(const bf16x8*)(aptr0 + (k + 1) * BK);
            na1 = *(const bf16x8*)(aptr1 + (k + 1) * BK);
        }

        const unsigned short* buf = blds[k & 1];
        #pragma unroll
        for (int mt = 0; mt < 16; ++mt) {
            bf16x8 bfr = *(const bf16x8*)&buf[mt * 512 + g * 128 + fr * 8];
            acc[0][mt] = __builtin_amdgcn_mfma_f32_16x16x32_bf16(a0, bfr, acc[0][mt], 0, 0, 0);
            acc[1][mt] = __builtin_amdgcn_mfma_f32_16x16x32_bf16(a1, bfr, acc[1][mt], 0, 0, 0);
        }
        a0 = na0; a1 = na1;
    }

    // ---- epilogue: per-row logsumexp over all 256 cols ----
    // C/D layout: col = mt*16 + (lane&15), row = (lane>>4)*4 + reg
    constexpr float INV_TAU_LN2 = 0.7213475204444817f;  // 1/(tau*ln2), tau=2
    constexpr float TAU_LN2     = 1.3862943611198906f;  // tau*ln2

    float row_acc = 0.0f;
    #pragma unroll
    for (int a = 0; a < 2; ++a) {
        #pragma unroll
        for (int r = 0; r < 4; ++r) {
            float vmax = acc[a][0][r];
            #pragma unroll
            for (int mt = 1; mt < 16; ++mt) vmax = fmaxf(vmax, acc[a][mt][r]);
            #pragma unroll
            for (int m = 1; m < 16; m <<= 1)
                vmax = fmaxf(vmax, __shfl_xor(vmax, m, 64));
            float s2 = 0.f;
            #pragma unroll
            for (int mt = 0; mt < 16; ++mt)
                s2 += exp2f((acc[a][mt][r] - vmax) * INV_TAU_LN2);
            #pragma unroll
            for (int m = 1; m < 16; m <<= 1)
                s2 += __shfl_xor(s2, m, 64);
            row_acc += vmax + TAU_LN2 * log2f(s2);
        }
    }

    row_acc += __shfl_xor(row_acc, 16, 64);
    row_acc += __shfl_xor(row_acc, 32, 64);
    if (lane == 0) wsum[wave] = row_acc;
    __syncthreads();
    if (tid == 0)
        atomicAdd(&out[bi * 32 + bj],
                  (wsum[0] + wsum[1] + wsum[2] + wsum[3]) * (1.0f / Na));
}

extern "C" void kernel_launch(void* const* d_in, const int* in_sizes, int n_in,
                              void* d_out, int out_size, void* d_ws, size_t ws_size,
                              hipStream_t stream) {
    const float* audio  = (const float*)d_in[0];
    const float* visual = (const float*)d_in[1];
    float* out = (float*)d_out;

    unsigned short* abf = (unsigned short*)d_ws;                 // 12.58 MB
    unsigned short* vbf = abf + (size_t)B_ * Na * D;             // +6.29 MB

    convert_kernel<<<dim3(2048), dim3(256), 0, stream>>>(audio, visual, abf, vbf, out);
    gemm_lse_kernel<<<dim3(B_ * B_ * NCH), dim3(256), 0, stream>>>(abf, vbf, out);
}